// Round 2
// baseline (214.713 us; speedup 1.0000x reference)
//
#include <hip/hip_runtime.h>
#include <hip/hip_bf16.h>

#define N_NODES 50000
#define N_EDGES 200000
// IN_C = 32, HID = 32, OUT_C = 16, EDGE_DIM = 8, EPS = 1e-5

// ---------------------------------------------------------------------------
// Kernel 1: h[n][o] = bias[o] + sum_i x[n][i] * root[i][o]
// One wave per node (grid-stride). Lane = (i2, o); root slice kept in regs.
// ---------------------------------------------------------------------------
__global__ __launch_bounds__(256, 2) void node_init_kernel(
    const float* __restrict__ x, const float* __restrict__ root,
    const float* __restrict__ bias, float* __restrict__ h)
{
    const int lane  = threadIdx.x & 63;
    const int o     = lane & 31;
    const int i2    = lane >> 5;
    const int ibase = i2 * 16;
    const int wid   = (blockIdx.x * blockDim.x + threadIdx.x) >> 6;
    const int nw    = (gridDim.x * blockDim.x) >> 6;

    float rreg[16];
#pragma unroll
    for (int ii = 0; ii < 16; ++ii)
        rreg[ii] = root[(ibase + ii) * 32 + o];
    const float b = bias[o];

    for (int n = wid; n < N_NODES; n += nw) {
        const float4* xp = (const float4*)(x + n * 32 + ibase);
        float4 xa = xp[0], xb = xp[1], xc = xp[2], xd = xp[3];
        float xs[16] = {xa.x, xa.y, xa.z, xa.w, xb.x, xb.y, xb.z, xb.w,
                        xc.x, xc.y, xc.z, xc.w, xd.x, xd.y, xd.z, xd.w};
        float acc = 0.f;
#pragma unroll
        for (int ii = 0; ii < 16; ++ii)
            acc = fmaf(xs[ii], rreg[ii], acc);
        acc += __shfl_xor(acc, 32);
        if (lane < 32) h[n * 32 + o] = acc + b;
    }
}

// ---------------------------------------------------------------------------
// Kernel 2: per edge e: W = relu(ea[e] @ nn_w + nn_b)  [32x32]
//           msg = x[src]^T @ W; atomicAdd into h[dst][:]
// One wave per edge (grid-stride). nn_w slice register-resident per lane.
// ---------------------------------------------------------------------------
__global__ __launch_bounds__(256, 2) void edge_kernel(
    const float* __restrict__ x, const int* __restrict__ ei,
    const float* __restrict__ ea, const float* __restrict__ nn_w,
    const float* __restrict__ nn_b, float* __restrict__ h)
{
    const int lane  = threadIdx.x & 63;
    const int o     = lane & 31;
    const int i2    = lane >> 5;
    const int ibase = i2 * 16;
    const int wid   = (blockIdx.x * blockDim.x + threadIdx.x) >> 6;
    const int nw    = (gridDim.x * blockDim.x) >> 6;

    // Preload weight slice: wreg[k][ii] = nn_w[k][ (ibase+ii)*32 + o ]
    float wreg[8][16];
    float breg[16];
#pragma unroll
    for (int ii = 0; ii < 16; ++ii) {
        breg[ii] = nn_b[(ibase + ii) * 32 + o];
#pragma unroll
        for (int k = 0; k < 8; ++k)
            wreg[k][ii] = nn_w[k * 1024 + (ibase + ii) * 32 + o];
    }

    for (int e = wid; e < N_EDGES; e += nw) {
        const int src = ei[e];
        const int dst = ei[N_EDGES + e];

        const float4* eap = (const float4*)(ea + (size_t)e * 8);
        const float4 e0 = eap[0];
        const float4 e1 = eap[1];

        const float4* xp = (const float4*)(x + (size_t)src * 32 + ibase);
        float4 xa = xp[0], xb = xp[1], xc = xp[2], xd = xp[3];
        float xs[16] = {xa.x, xa.y, xa.z, xa.w, xb.x, xb.y, xb.z, xb.w,
                        xc.x, xc.y, xc.z, xc.w, xd.x, xd.y, xd.z, xd.w};

        float msg = 0.f;
#pragma unroll
        for (int ii = 0; ii < 16; ++ii) {
            float a = breg[ii];
            a = fmaf(e0.x, wreg[0][ii], a);
            a = fmaf(e0.y, wreg[1][ii], a);
            a = fmaf(e0.z, wreg[2][ii], a);
            a = fmaf(e0.w, wreg[3][ii], a);
            a = fmaf(e1.x, wreg[4][ii], a);
            a = fmaf(e1.y, wreg[5][ii], a);
            a = fmaf(e1.z, wreg[6][ii], a);
            a = fmaf(e1.w, wreg[7][ii], a);
            a = fmaxf(a, 0.f);
            msg = fmaf(xs[ii], a, msg);
        }
        msg += __shfl_xor(msg, 32);
        if (lane < 32)
            unsafeAtomicAdd(&h[(size_t)dst * 32 + o], msg);
    }
}

// ---------------------------------------------------------------------------
// Kernel 3: LayerNorm(h) -> relu -> @ lin_w + lin_b  -> out [N,16]
// Block of 256 = 8 nodes x 32 lanes. LN via shfl_xor butterflies.
// ---------------------------------------------------------------------------
__global__ __launch_bounds__(256) void finalize_kernel(
    const float* __restrict__ h, const float* __restrict__ norm_w,
    const float* __restrict__ norm_b, const float* __restrict__ lin_w,
    const float* __restrict__ lin_b, float* __restrict__ out)
{
    __shared__ float vsh[8 * 32];
    __shared__ float lwsh[32 * 16];

    const int t = threadIdx.x;
    // preload lin_w (512 floats) into LDS
    lwsh[t] = lin_w[t];
    lwsh[t + 256] = lin_w[t + 256];

    const int nl = t >> 5;   // 0..7 node within block
    const int o  = t & 31;
    const int n  = blockIdx.x * 8 + nl;

    float v = h[(size_t)n * 32 + o];

    // mean over 32 (masks <32 stay within the 32-lane group)
    float s = v;
#pragma unroll
    for (int m = 1; m < 32; m <<= 1) s += __shfl_xor(s, m);
    const float mu = s * (1.f / 32.f);
    const float d  = v - mu;
    float q = d * d;
#pragma unroll
    for (int m = 1; m < 32; m <<= 1) q += __shfl_xor(q, m);
    const float var = q * (1.f / 32.f);

    float nv = d * rsqrtf(var + 1e-5f) * norm_w[o] + norm_b[o];
    vsh[t] = fmaxf(nv, 0.f);
    __syncthreads();

    if (t < 128) {
        const int n2 = t >> 4;   // 0..7
        const int j  = t & 15;   // 0..15
        const float* vp = vsh + n2 * 32;
        float acc = lin_b[j];
#pragma unroll
        for (int o2 = 0; o2 < 32; ++o2)
            acc = fmaf(vp[o2], lwsh[o2 * 16 + j], acc);
        out[(size_t)(blockIdx.x * 8 + n2) * 16 + j] = acc;
    }
}

// ---------------------------------------------------------------------------
extern "C" void kernel_launch(void* const* d_in, const int* in_sizes, int n_in,
                              void* d_out, int out_size, void* d_ws, size_t ws_size,
                              hipStream_t stream)
{
    const float* x      = (const float*)d_in[0];
    const int*   ei     = (const int*)  d_in[1];
    const float* ea     = (const float*)d_in[2];
    const float* nn_w   = (const float*)d_in[3];
    const float* nn_b   = (const float*)d_in[4];
    const float* root   = (const float*)d_in[5];
    const float* bias   = (const float*)d_in[6];
    const float* norm_w = (const float*)d_in[7];
    const float* norm_b = (const float*)d_in[8];
    const float* lin_w  = (const float*)d_in[9];
    const float* lin_b  = (const float*)d_in[10];
    float* out = (float*)d_out;

    float* h = (float*)d_ws;   // N_NODES * 32 floats = 6.4 MB

    node_init_kernel<<<512, 256, 0, stream>>>(x, root, bias, h);
    edge_kernel<<<1024, 256, 0, stream>>>(x, ei, ea, nn_w, nn_b, h);
    finalize_kernel<<<N_NODES / 8, 256, 0, stream>>>(h, norm_w, norm_b,
                                                     lin_w, lin_b, out);
}

// Round 3
// 192.541 us; speedup vs baseline: 1.1152x; 1.1152x over previous
//
#include <hip/hip_runtime.h>
#include <hip/hip_bf16.h>

#define N_NODES 50000
#define N_EDGES 200000
// IN_C = 32, HID = 32, OUT_C = 16, EDGE_DIM = 8, EPS = 1e-5

typedef float v2f __attribute__((ext_vector_type(2)));

static __device__ inline v2f sp2(float s) { v2f r; r.x = s; r.y = s; return r; }

static __device__ inline v2f fma2(v2f a, v2f b, v2f c) {
#if __has_builtin(__builtin_elementwise_fma)
    return __builtin_elementwise_fma(a, b, c);
#else
    v2f r; r.x = fmaf(a.x, b.x, c.x); r.y = fmaf(a.y, b.y, c.y); return r;
#endif
}

static __device__ inline v2f max2(v2f a, v2f b) {
#if __has_builtin(__builtin_elementwise_max)
    return __builtin_elementwise_max(a, b);
#else
    v2f r; r.x = fmaxf(a.x, b.x); r.y = fmaxf(a.y, b.y); return r;
#endif
}

// ---------------------------------------------------------------------------
// Edge kernel: per edge e: W = relu(ea[e] @ nn_w + nn_b)  [32x32]
//              msg = x[src]^T @ W; atomicAdd into agg[dst][:]
// One wave per edge (grid-stride, persistent: 2048 waves = 2/SIMD resident).
// Lane = (i2, o). Weight slice PINNED in VGPRs (asm) — ~128 regs.
// Packed fp32 (v_pk_fma_f32) over input-channel pairs.
// 1-deep software pipeline: next edge's ei/ea loaded at top, x[srcn] loads
// fused after each xs[j]'s last use.
// ---------------------------------------------------------------------------
__global__ __launch_bounds__(256, 2) void edge_kernel(
    const float* __restrict__ x, const int* __restrict__ ei,
    const float* __restrict__ ea, const float* __restrict__ nn_w,
    const float* __restrict__ nn_b, float* __restrict__ agg)
{
    const int lane  = threadIdx.x & 63;
    const int o     = lane & 31;
    const int ibase = (lane >> 5) * 16;
    const int wid   = (blockIdx.x * blockDim.x + threadIdx.x) >> 6;
    const int nw    = (gridDim.x * blockDim.x) >> 6;

    // wreg[k][j] = { nn_w[k][(ibase+2j)*32+o], nn_w[k][(ibase+2j+1)*32+o] }
    v2f wreg[8][8], breg[8];
#pragma unroll
    for (int j = 0; j < 8; ++j) {
        const int i0 = ibase + 2 * j;
        v2f b; b.x = nn_b[i0 * 32 + o]; b.y = nn_b[(i0 + 1) * 32 + o];
        breg[j] = b;
#pragma unroll
        for (int k = 0; k < 8; ++k) {
            v2f w;
            w.x = nn_w[k * 1024 + i0 * 32 + o];
            w.y = nn_w[k * 1024 + (i0 + 1) * 32 + o];
            wreg[k][j] = w;
        }
    }
    // Pin in VGPRs: value now defined by inline asm -> not rematerializable.
#pragma unroll
    for (int j = 0; j < 8; ++j) {
        asm volatile("" : "+v"(breg[j]));
#pragma unroll
        for (int k = 0; k < 8; ++k)
            asm volatile("" : "+v"(wreg[k][j]));
    }

    int e = wid;
    if (e >= N_EDGES) return;

    int src = ei[e];
    int dst = ei[N_EDGES + e];
    float4 c0 = ((const float4*)(ea + (size_t)e * 8))[0];
    float4 c1 = ((const float4*)(ea + (size_t)e * 8))[1];
    v2f xs[8];
    {
        const v2f* xp = (const v2f*)(x + (size_t)src * 32 + ibase);
#pragma unroll
        for (int j = 0; j < 8; ++j) xs[j] = xp[j];
    }

    while (true) {
        const int  en       = e + nw;
        const bool has_next = (en < N_EDGES);
        const int  enc      = has_next ? en : e;   // clamped: loads always valid

        // --- prefetch next edge's metadata (issue early) ---
        const int srcn = ei[enc];
        const int dstn = ei[N_EDGES + enc];
        const float4 n0 = ((const float4*)(ea + (size_t)enc * 8))[0];
        const float4 n1 = ((const float4*)(ea + (size_t)enc * 8))[1];

        // --- MLP first half (k=0..3): 32 pk_fma, hides srcn load latency ---
        v2f acc[8];
#pragma unroll
        for (int j = 0; j < 8; ++j) acc[j] = breg[j];
#pragma unroll
        for (int j = 0; j < 8; ++j) {
            acc[j] = fma2(sp2(c0.x), wreg[0][j], acc[j]);
            acc[j] = fma2(sp2(c0.y), wreg[1][j], acc[j]);
            acc[j] = fma2(sp2(c0.z), wreg[2][j], acc[j]);
            acc[j] = fma2(sp2(c0.w), wreg[3][j], acc[j]);
        }

        // --- MLP second half + relu + msg; prefetch x[srcn] per-j after last
        //     use of xs[j] (reuses the same registers) ---
        const v2f* xpn = (const v2f*)(x + (size_t)srcn * 32 + ibase);
        v2f m2 = sp2(0.f);
#pragma unroll
        for (int j = 0; j < 8; ++j) {
            acc[j] = fma2(sp2(c1.x), wreg[4][j], acc[j]);
            acc[j] = fma2(sp2(c1.y), wreg[5][j], acc[j]);
            acc[j] = fma2(sp2(c1.z), wreg[6][j], acc[j]);
            acc[j] = fma2(sp2(c1.w), wreg[7][j], acc[j]);
            acc[j] = max2(acc[j], sp2(0.f));
            m2 = fma2(xs[j], acc[j], m2);
            xs[j] = xpn[j];                       // prefetch for next iter
        }

        float msg = m2.x + m2.y;
        msg += __shfl_xor(msg, 32);
        if (lane < 32)
            unsafeAtomicAdd(&agg[(size_t)dst * 32 + o], msg);

        if (!has_next) break;
        e = en; src = srcn; dst = dstn; c0 = n0; c1 = n1;
    }
}

// ---------------------------------------------------------------------------
// Finalize (fused): h = agg + x@root + bias -> LayerNorm -> relu -> @lin_w+lin_b
// One wave per node (grid-stride). Lane=(i2,o) for the root matvec; LN via
// shfl butterflies (both 32-lane halves duplicate); linear via lane=(o2,j).
// ---------------------------------------------------------------------------
__global__ __launch_bounds__(256) void finalize_kernel(
    const float* __restrict__ agg, const float* __restrict__ x,
    const float* __restrict__ root, const float* __restrict__ bias,
    const float* __restrict__ norm_w, const float* __restrict__ norm_b,
    const float* __restrict__ lin_w, const float* __restrict__ lin_b,
    float* __restrict__ out)
{
    const int lane  = threadIdx.x & 63;
    const int o     = lane & 31;
    const int ibase = (lane >> 5) * 16;
    const int wid   = (blockIdx.x * blockDim.x + threadIdx.x) >> 6;
    const int nw    = (gridDim.x * blockDim.x) >> 6;

    // root slice: rreg[j] = { root[(ibase+2j)*32+o], root[(ibase+2j+1)*32+o] }
    v2f rreg[8];
#pragma unroll
    for (int j = 0; j < 8; ++j) {
        const int i0 = ibase + 2 * j;
        v2f r; r.x = root[i0 * 32 + o]; r.y = root[(i0 + 1) * 32 + o];
        rreg[j] = r;
    }
#pragma unroll
    for (int j = 0; j < 8; ++j) asm volatile("" : "+v"(rreg[j]));

    const float bv  = bias[o];
    const float nwv = norm_w[o];
    const float nbv = norm_b[o];

    // linear stage layout: lane = (o2 = lane>>4 in 0..3, j15 = lane&15)
    const int j15 = lane & 15;
    const int o2  = lane >> 4;
    float lwreg[8];
#pragma unroll
    for (int t = 0; t < 8; ++t) lwreg[t] = lin_w[(o2 * 8 + t) * 16 + j15];
    const float lbv = lin_b[j15];

    for (int n = wid; n < N_NODES; n += nw) {
        // root matvec (packed, split over i2 halves)
        const v2f* xp = (const v2f*)(x + (size_t)n * 32 + ibase);
        v2f r2 = sp2(0.f);
#pragma unroll
        for (int j = 0; j < 8; ++j) r2 = fma2(xp[j], rreg[j], r2);
        float r = r2.x + r2.y;
        r += __shfl_xor(r, 32);   // all 64 lanes: full dot for o = lane&31

        float hv = agg[(size_t)n * 32 + o] + r + bv;

        // LayerNorm over the 32 o's (masks stay within 32-lane group)
        float s = hv;
#pragma unroll
        for (int m = 1; m < 32; m <<= 1) s += __shfl_xor(s, m);
        const float mu = s * (1.f / 32.f);
        const float d  = hv - mu;
        float q = d * d;
#pragma unroll
        for (int m = 1; m < 32; m <<= 1) q += __shfl_xor(q, m);
        const float var = q * (1.f / 32.f);

        const float rv = fmaxf(d * rsqrtf(var + 1e-5f) * nwv + nbv, 0.f);

        // linear 32->16: lane (o2,j15) partial over 8 o's, then reduce
        float acc = 0.f;
#pragma unroll
        for (int t = 0; t < 8; ++t) {
            const float v = __shfl(rv, o2 * 8 + t, 64);  // rv lives at lane=o
            acc = fmaf(v, lwreg[t], acc);
        }
        acc += __shfl_xor(acc, 16);
        acc += __shfl_xor(acc, 32);
        if (lane < 16)
            out[(size_t)n * 16 + lane] = acc + lbv;
    }
}

// ---------------------------------------------------------------------------
extern "C" void kernel_launch(void* const* d_in, const int* in_sizes, int n_in,
                              void* d_out, int out_size, void* d_ws, size_t ws_size,
                              hipStream_t stream)
{
    const float* x      = (const float*)d_in[0];
    const int*   ei     = (const int*)  d_in[1];
    const float* ea     = (const float*)d_in[2];
    const float* nn_w   = (const float*)d_in[3];
    const float* nn_b   = (const float*)d_in[4];
    const float* root   = (const float*)d_in[5];
    const float* bias   = (const float*)d_in[6];
    const float* norm_w = (const float*)d_in[7];
    const float* norm_b = (const float*)d_in[8];
    const float* lin_w  = (const float*)d_in[9];
    const float* lin_b  = (const float*)d_in[10];
    float* out = (float*)d_out;

    float* agg = (float*)d_ws;   // N_NODES * 32 floats = 6.4 MB

    hipMemsetAsync(agg, 0, (size_t)N_NODES * 32 * sizeof(float), stream);
    edge_kernel<<<512, 256, 0, stream>>>(x, ei, ea, nn_w, nn_b, agg);
    finalize_kernel<<<1024, 256, 0, stream>>>(agg, x, root, bias, norm_w,
                                              norm_b, lin_w, lin_b, out);
}